// Round 11
// baseline (161.278 us; speedup 1.0000x reference)
//
#include <hip/hip_runtime.h>

// S6 selective scan: BT=8, L=8192, F=128, N=16
// Chunked matmul reformulation (stable, per-n diagonal A):
//   Mtot(t,s) = sum_n C(t,n) dB(s,n) exp(A_n (cum(t)-cum(s)))   [t>=s, else 0]
//   y_local   = Mtot @ X
//   q[n,f]    = sum_s dB(s,n) exp(A_n (S-cum(s))) X(s,f)
//   y        += E @ Hin,  E(t,n) = C(t,n) exp(A_n cum(t))
//
// k_pre       : proj -> G{dB[16],C[16]}, cumG (within-chunk inclusive), S
// k_ymm       : per chunk: build Mtot,Fq in LDS; y_local = Mtot@X, q = Fq@X
// k_chunkscan : serial scan over chunks -> Hin
// k_correct   : y += E @ Hin (E rebuilt from C,cum)
//
// Round-11 fix: Mt was declared [LC][36] but used 64-wide (row aliasing ->
// garbage output). Now [LC][68]. k_ymm launch_bounds (256,3) to avoid
// forcing X[64] into scratch (128-VGPR cap at 4 waves/EU was borderline).

#define BTc   8
#define Lseq  8192
#define Fdim  128
#define Ndim  16
#define CH    128
#define LC    64
#define LOG2E 1.44269504089f

// 512 blocks x 256 thr; thread=(t2,ks): tokens blk*128+t2 and +64, K-quarter ks
__global__ __launch_bounds__(256) void k_pre(
    const float* __restrict__ x,
    const float* __restrict__ Wb, const float* __restrict__ bb,
    const float* __restrict__ Wc, const float* __restrict__ bc,
    const float* __restrict__ Wd, const float* __restrict__ bd,
    const float* __restrict__ A,  float* __restrict__ G,
    float* __restrict__ cumG, float* __restrict__ S)
{
    __shared__ float Wl[33][4][36];   // 19 KB, ks-slices in distinct banks
    __shared__ float Dl[2][64];
    __shared__ float Cum[2][64];
    const int tid = threadIdx.x;
    for (int idx = tid; idx < 33 * 128; idx += 256) {
        int j = idx >> 7, k = idx & 127;
        float v;
        if (j < 16)      v = Wb[k * 16 + j];
        else if (j < 32) v = Wc[k * 16 + (j - 16)];
        else             v = Wd[k];
        Wl[j][k >> 5][k & 31] = v;
    }
    __syncthreads();

    const int t2 = tid >> 2, ks = tid & 3;
    const size_t gtok0 = (size_t)blockIdx.x * 128;
    const size_t tokA = gtok0 + t2;
    const float4* xA = reinterpret_cast<const float4*>(x + tokA * 128 + ks * 32);
    const float4* xB = reinterpret_cast<const float4*>(x + (tokA + 64) * 128 + ks * 32);

    float accA[33], accB[33];
#pragma unroll
    for (int j = 0; j < 33; ++j) { accA[j] = 0.f; accB[j] = 0.f; }

#pragma unroll 2
    for (int kk = 0; kk < 8; ++kk) {
        float4 a = xA[kk], b = xB[kk];
#pragma unroll
        for (int j = 0; j < 33; ++j) {
            float4 w = *reinterpret_cast<const float4*>(&Wl[j][ks][kk * 4]);
            accA[j] = fmaf(a.x, w.x, accA[j]);
            accA[j] = fmaf(a.y, w.y, accA[j]);
            accA[j] = fmaf(a.z, w.z, accA[j]);
            accA[j] = fmaf(a.w, w.w, accA[j]);
            accB[j] = fmaf(b.x, w.x, accB[j]);
            accB[j] = fmaf(b.y, w.y, accB[j]);
            accB[j] = fmaf(b.z, w.z, accB[j]);
            accB[j] = fmaf(b.w, w.w, accB[j]);
        }
    }

    float sel[33];
#pragma unroll
    for (int j = 0; j < 33; ++j) {
        accA[j] += __shfl_xor(accA[j], 1);
        accA[j] += __shfl_xor(accA[j], 2);
        accB[j] += __shfl_xor(accB[j], 1);
        accB[j] += __shfl_xor(accB[j], 2);
        sel[j] = (ks & 1) ? accB[j] : accA[j];
    }

    if (ks < 2) {                      // ks=0 -> token A, ks=1 -> token B
        const size_t tok = gtok0 + (size_t)ks * 64 + t2;
        float v = sel[32] + bd[0];
        float delta = fmaxf(v, 0.f) + log1pf(expf(-fabsf(v)));
        Dl[ks][t2] = delta;
        float out[32];
#pragma unroll
        for (int n = 0; n < 16; ++n) {
            float An = A[n];
            float dA = expf(delta * An);
            out[n]      = (dA - 1.f) / An * (sel[n] + bb[n]);   // dB
            out[16 + n] = sel[16 + n] + bc[n];                  // C
        }
        float4* Gr = reinterpret_cast<float4*>(G + tok * 32);
#pragma unroll
        for (int p = 0; p < 8; ++p)
            Gr[p] = make_float4(out[4*p], out[4*p+1], out[4*p+2], out[4*p+3]);
    }
    __syncthreads();

    if (tid < 128) {
        const int w = tid >> 6, lane = tid & 63;
        float cum = Dl[w][lane];
#pragma unroll
        for (int off = 1; off < 64; off <<= 1) {
            float up = __shfl_up(cum, off);
            cum += (lane >= off) ? up : 0.f;
        }
        Cum[w][lane] = cum;
        if (lane == 63) S[blockIdx.x * 2 + w] = cum;
    }
    __syncthreads();
    if (tid < 128) cumG[gtok0 + tid] = Cum[tid >> 6][tid & 63];
}

// grid (CH, BTc) x 256 thr: build Mtot/Fq, then y_local = Mt@X, q = Fq@X
__global__ __launch_bounds__(256, 3) void k_ymm(
    const float* __restrict__ x, const float* __restrict__ G,
    const float* __restrict__ cumG, const float* __restrict__ S,
    const float* __restrict__ A,
    float* __restrict__ y, float* __restrict__ q)
{
    __shared__ float Gt[LC][36];      // dB[0..15] | C[16..31], padded rows
    __shared__ float argT[LC][16];    // A2_n * cum_t
    __shared__ float Mt[LC][68];      // causal kernel matrix, 64 wide + pad
    __shared__ float Fq[16][68];      // Fq[n][s]
    __shared__ float cumL[LC];
    __shared__ float A2l[16];

    const int tid = threadIdx.x;
    const int c = blockIdx.x, b = blockIdx.y;
    const size_t tok0 = (size_t)b * Lseq + (size_t)c * LC;

    // ---- stage ----
    {
        const float4* Gg = reinterpret_cast<const float4*>(G + tok0 * 32);
        for (int i = tid; i < 512; i += 256) {
            int t = i >> 3, p = i & 7;
            *reinterpret_cast<float4*>(&Gt[t][p * 4]) = Gg[i];
        }
        if (tid < 64) cumL[tid] = cumG[tok0 + tid];
        if (tid < 16) A2l[tid] = A[tid] * LOG2E;
    }
    const int f = tid & 127;
    float X[64];
    {
        const float* xp = x + tok0 * Fdim + f;
#pragma unroll
        for (int s = 0; s < 64; ++s) X[s] = xp[s * Fdim];
    }
    const float Sc = S[b * CH + c];
    __syncthreads();

    // ---- phase 1: argT + Fq ----
    for (int i = tid; i < 1024; i += 256) {
        int t = i >> 4, n = i & 15;
        argT[t][n] = A2l[n] * cumL[t];
    }
    for (int i = tid; i < 1024; i += 256) {
        int nn = i >> 6, s = i & 63;
        Fq[nn][s] = Gt[s][nn] * exp2f(A2l[nn] * (Sc - cumL[s]));
    }
    __syncthreads();

    // ---- phase 2: build Mt (thread: fixed s = tid&63, t = 4k + (tid>>6)) ----
    {
        const int s = tid & 63;
        const int w = tid >> 6;
        float dBs[16], args[16];
#pragma unroll
        for (int n = 0; n < 16; ++n) { dBs[n] = Gt[s][n]; args[n] = argT[s][n]; }
        for (int k = 0; k < 16; ++k) {
            int t = 4 * k + w;
            const float4* Ct = reinterpret_cast<const float4*>(&Gt[t][16]);
            const float4* at = reinterpret_cast<const float4*>(&argT[t][0]);
            float acc = 0.f;
#pragma unroll
            for (int p = 0; p < 4; ++p) {
                float4 c4 = Ct[p], a4 = at[p];
                acc = fmaf(c4.x * dBs[4*p],   exp2f(a4.x - args[4*p]),   acc);
                acc = fmaf(c4.y * dBs[4*p+1], exp2f(a4.y - args[4*p+1]), acc);
                acc = fmaf(c4.z * dBs[4*p+2], exp2f(a4.z - args[4*p+2]), acc);
                acc = fmaf(c4.w * dBs[4*p+3], exp2f(a4.w - args[4*p+3]), acc);
            }
            Mt[t][s] = (s <= t) ? acc : 0.f;   // mask kills inf garbage from s>t
        }
    }
    __syncthreads();

    // ---- phase 3: y_local = Mt @ X (causal), q = Fq @ X ----
    {
        const int h = tid >> 7;          // t-parity / n-half
        float* yp = y + tok0 * Fdim + f;
#pragma unroll
        for (int k = 0; k < 32; ++k) {
            const int ns4 = ((2 * k + 1) >> 2) + 1;   // covers s<=t, rest masked 0
            int t = 2 * k + h;
            const float4* Mrow = reinterpret_cast<const float4*>(&Mt[t][0]);
            float a0 = 0.f, a1 = 0.f, a2 = 0.f, a3 = 0.f;
#pragma unroll
            for (int s4 = 0; s4 < ns4; ++s4) {
                float4 m4 = Mrow[s4];
                a0 = fmaf(m4.x, X[4*s4],     a0);
                a1 = fmaf(m4.y, X[4*s4 + 1], a1);
                a2 = fmaf(m4.z, X[4*s4 + 2], a2);
                a3 = fmaf(m4.w, X[4*s4 + 3], a3);
            }
            yp[t * Fdim] = (a0 + a1) + (a2 + a3);
        }
        float4* qp = reinterpret_cast<float4*>(q + ((size_t)(b * CH + c) * Fdim + f) * 16 + h * 8);
#pragma unroll
        for (int nb = 0; nb < 2; ++nb) {
            float qv[4];
#pragma unroll
            for (int j = 0; j < 4; ++j) {
                const float4* Fr = reinterpret_cast<const float4*>(&Fq[h * 8 + nb * 4 + j][0]);
                float b0 = 0.f, b1 = 0.f, b2 = 0.f, b3 = 0.f;
#pragma unroll
                for (int s4 = 0; s4 < 16; ++s4) {
                    float4 f4 = Fr[s4];
                    b0 = fmaf(f4.x, X[4*s4],     b0);
                    b1 = fmaf(f4.y, X[4*s4 + 1], b1);
                    b2 = fmaf(f4.z, X[4*s4 + 2], b2);
                    b3 = fmaf(f4.w, X[4*s4 + 3], b3);
                }
                qv[j] = (b0 + b1) + (b2 + b3);
            }
            qp[nb] = make_float4(qv[0], qv[1], qv[2], qv[3]);
        }
    }
}

__global__ __launch_bounds__(256) void k_chunkscan(
    const float* __restrict__ q, const float* __restrict__ S,
    const float* __restrict__ A, float* __restrict__ Hin)
{
    int id = blockIdx.x * 256 + threadIdx.x;   // 16384 = 8*128*16
    int b  = id >> 11;
    int fn = id & 2047;
    int n  = id & 15;
    float An = A[n];
    float H = 0.f;
    size_t qb = (size_t)b * CH * 2048 + fn;
    const float* Sb = S + b * CH;
    for (int cg = 0; cg < CH; cg += 16) {
        float Sr[16], qr[16];
#pragma unroll
        for (int i = 0; i < 16; ++i) {
            Sr[i] = Sb[cg + i];
            qr[i] = q[qb + (size_t)(cg + i) * 2048];
        }
#pragma unroll
        for (int i = 0; i < 16; ++i) {
            Hin[qb + (size_t)(cg + i) * 2048] = H;
            H = fmaf(__expf(An * Sr[i]), H, qr[i]);
        }
    }
}

// grid (CH, BTc) x 128 thr: y += E @ Hin, E rebuilt from C,cum
__global__ __launch_bounds__(128) void k_correct(
    const float* __restrict__ G, const float* __restrict__ cumG,
    const float* __restrict__ A, const float* __restrict__ Hin,
    float* __restrict__ y)
{
    __shared__ float El[LC][16];
    __shared__ float cumL[LC];
    const int c = blockIdx.x, b = blockIdx.y;
    const int f = threadIdx.x;
    const size_t tok0 = (size_t)b * Lseq + (size_t)c * LC;

    if (f < 64) cumL[f] = cumG[tok0 + f];

    float hv[16];
    const float4* hp = reinterpret_cast<const float4*>(Hin + ((size_t)(b * CH + c) * Fdim + f) * 16);
#pragma unroll
    for (int p = 0; p < 4; ++p) {
        float4 t4 = hp[p];
        hv[4*p] = t4.x; hv[4*p+1] = t4.y; hv[4*p+2] = t4.z; hv[4*p+3] = t4.w;
    }
    __syncthreads();

    for (int i = f; i < 1024; i += 128) {
        int t = i >> 4, n = i & 15;
        float A2n = A[n] * LOG2E;
        El[t][n] = G[(tok0 + t) * 32 + 16 + n] * exp2f(A2n * cumL[t]);
    }
    __syncthreads();

    float* yp = y + tok0 * Fdim + f;
#pragma unroll 4
    for (int t = 0; t < LC; ++t) {
        const float4* ep = reinterpret_cast<const float4*>(&El[t][0]);
        float acc = 0.f;
#pragma unroll
        for (int p = 0; p < 4; ++p) {
            float4 e4 = ep[p];
            acc = fmaf(e4.x, hv[4*p],     acc);
            acc = fmaf(e4.y, hv[4*p + 1], acc);
            acc = fmaf(e4.z, hv[4*p + 2], acc);
            acc = fmaf(e4.w, hv[4*p + 3], acc);
        }
        yp[t * Fdim] += acc;
    }
}

extern "C" void kernel_launch(void* const* d_in, const int* in_sizes, int n_in,
                              void* d_out, int out_size, void* d_ws, size_t ws_size,
                              hipStream_t stream) {
    const float* x  = (const float*)d_in[0];
    const float* Wb = (const float*)d_in[1];
    const float* bb = (const float*)d_in[2];
    const float* Wc = (const float*)d_in[3];
    const float* bc = (const float*)d_in[4];
    const float* Wd = (const float*)d_in[5];
    const float* bd = (const float*)d_in[6];
    const float* A  = (const float*)d_in[7];
    float* y = (float*)d_out;

    float* G    = (float*)d_ws;                            // 65536*32 = 8.4 MB
    float* q    = G    + (size_t)BTc * Lseq * 32;          // 8.4 MB
    float* Hin  = q    + (size_t)BTc * CH * Fdim * Ndim;   // 8.4 MB
    float* cumG = Hin  + (size_t)BTc * CH * Fdim * Ndim;   // 0.26 MB
    float* S    = cumG + (size_t)BTc * Lseq;               // 4 KB

    k_pre<<<dim3(512), 256, 0, stream>>>(x, Wb, bb, Wc, bc, Wd, bd, A, G, cumG, S);
    k_ymm<<<dim3(CH, BTc), 256, 0, stream>>>(x, G, cumG, S, A, y, q);
    k_chunkscan<<<dim3(BTc * Fdim * Ndim / 256), 256, 0, stream>>>(q, S, A, Hin);
    k_correct<<<dim3(CH, BTc), 128, 0, stream>>>(G, cumG, A, Hin, y);
}

// Round 12
// 107.762 us; speedup vs baseline: 1.4966x; 1.4966x over previous
//
#include <hip/hip_runtime.h>

// S6 selective scan: BT=8, L=8192, F=128, N=16
// Chunked matmul reformulation (stable, per-n diagonal A):
//   Mtot(t,s) = sum_n C(t,n) dB(s,n) exp(A_n (cum(t)-cum(s)))   [t>=s, else 0]
//   y_local   = Mtot @ X
//   q[n,f]    = sum_s dB(s,n) exp(A_n (S-cum(s))) X(s,f)
//   y        += E @ Hin,  E(t,n) = C(t,n) exp(A_n cum(t))
//
// Round-12: fixed X-spill (constant-trip inner loops -> compile-time X idx),
// 2 f/thread (halves LDS broadcasts), launch_bounds(256,2).

#define BTc   8
#define Lseq  8192
#define Fdim  128
#define Ndim  16
#define CH    128
#define LC    64
#define LOG2E 1.44269504089f

// 512 blocks x 256 thr; thread=(t2,ks): tokens blk*128+t2 and +64, K-quarter ks
__global__ __launch_bounds__(256) void k_pre(
    const float* __restrict__ x,
    const float* __restrict__ Wb, const float* __restrict__ bb,
    const float* __restrict__ Wc, const float* __restrict__ bc,
    const float* __restrict__ Wd, const float* __restrict__ bd,
    const float* __restrict__ A,  float* __restrict__ G,
    float* __restrict__ cumG, float* __restrict__ S)
{
    __shared__ float Wl[33][4][36];   // 19 KB, ks-slices in distinct banks
    __shared__ float Dl[2][64];
    __shared__ float Cum[2][64];
    const int tid = threadIdx.x;
    for (int idx = tid; idx < 33 * 128; idx += 256) {
        int j = idx >> 7, k = idx & 127;
        float v;
        if (j < 16)      v = Wb[k * 16 + j];
        else if (j < 32) v = Wc[k * 16 + (j - 16)];
        else             v = Wd[k];
        Wl[j][k >> 5][k & 31] = v;
    }
    __syncthreads();

    const int t2 = tid >> 2, ks = tid & 3;
    const size_t gtok0 = (size_t)blockIdx.x * 128;
    const size_t tokA = gtok0 + t2;
    const float4* xA = reinterpret_cast<const float4*>(x + tokA * 128 + ks * 32);
    const float4* xB = reinterpret_cast<const float4*>(x + (tokA + 64) * 128 + ks * 32);

    float accA[33], accB[33];
#pragma unroll
    for (int j = 0; j < 33; ++j) { accA[j] = 0.f; accB[j] = 0.f; }

#pragma unroll 2
    for (int kk = 0; kk < 8; ++kk) {
        float4 a = xA[kk], b = xB[kk];
#pragma unroll
        for (int j = 0; j < 33; ++j) {
            float4 w = *reinterpret_cast<const float4*>(&Wl[j][ks][kk * 4]);
            accA[j] = fmaf(a.x, w.x, accA[j]);
            accA[j] = fmaf(a.y, w.y, accA[j]);
            accA[j] = fmaf(a.z, w.z, accA[j]);
            accA[j] = fmaf(a.w, w.w, accA[j]);
            accB[j] = fmaf(b.x, w.x, accB[j]);
            accB[j] = fmaf(b.y, w.y, accB[j]);
            accB[j] = fmaf(b.z, w.z, accB[j]);
            accB[j] = fmaf(b.w, w.w, accB[j]);
        }
    }

    float sel[33];
#pragma unroll
    for (int j = 0; j < 33; ++j) {
        accA[j] += __shfl_xor(accA[j], 1);
        accA[j] += __shfl_xor(accA[j], 2);
        accB[j] += __shfl_xor(accB[j], 1);
        accB[j] += __shfl_xor(accB[j], 2);
        sel[j] = (ks & 1) ? accB[j] : accA[j];
    }

    if (ks < 2) {                      // ks=0 -> token A, ks=1 -> token B
        const size_t tok = gtok0 + (size_t)ks * 64 + t2;
        float v = sel[32] + bd[0];
        float delta = fmaxf(v, 0.f) + log1pf(expf(-fabsf(v)));
        Dl[ks][t2] = delta;
        float out[32];
#pragma unroll
        for (int n = 0; n < 16; ++n) {
            float An = A[n];
            float dA = expf(delta * An);
            out[n]      = (dA - 1.f) / An * (sel[n] + bb[n]);   // dB
            out[16 + n] = sel[16 + n] + bc[n];                  // C
        }
        float4* Gr = reinterpret_cast<float4*>(G + tok * 32);
#pragma unroll
        for (int p = 0; p < 8; ++p)
            Gr[p] = make_float4(out[4*p], out[4*p+1], out[4*p+2], out[4*p+3]);
    }
    __syncthreads();

    if (tid < 128) {
        const int w = tid >> 6, lane = tid & 63;
        float cum = Dl[w][lane];
#pragma unroll
        for (int off = 1; off < 64; off <<= 1) {
            float up = __shfl_up(cum, off);
            cum += (lane >= off) ? up : 0.f;
        }
        Cum[w][lane] = cum;
        if (lane == 63) S[blockIdx.x * 2 + w] = cum;
    }
    __syncthreads();
    if (tid < 128) cumG[gtok0 + tid] = Cum[tid >> 6][tid & 63];
}

// grid (CH, BTc) x 256 thr: build Mtot/Fq, then y_local = Mt@X, q = Fq@X
// phase3 mapping: lane=tid&63 owns f=2*lane,2*lane+1; wave w owns t=4k+w / n=4w+j
__global__ __launch_bounds__(256, 2) void k_ymm(
    const float* __restrict__ x, const float* __restrict__ G,
    const float* __restrict__ cumG, const float* __restrict__ S,
    const float* __restrict__ A,
    float* __restrict__ y, float* __restrict__ q)
{
    __shared__ float Gt[LC][36];      // dB[0..15] | C[16..31], padded rows
    __shared__ float argT[LC][16];    // A2_n * cum_t
    __shared__ float Mt[LC][68];      // causal kernel matrix, 64 wide + pad
    __shared__ float Fq[16][68];      // Fq[n][s]
    __shared__ float cumL[LC];
    __shared__ float A2l[16];

    const int tid = threadIdx.x;
    const int lane = tid & 63;
    const int w = tid >> 6;
    const int c = blockIdx.x, b = blockIdx.y;
    const size_t tok0 = (size_t)b * Lseq + (size_t)c * LC;

    // ---- X load: f-pair (2*lane, 2*lane+1), coalesced float2 ----
    float2 Xv[64];
    {
        const float2* xp = reinterpret_cast<const float2*>(x + tok0 * Fdim) + lane;
#pragma unroll
        for (int s = 0; s < 64; ++s) Xv[s] = xp[s * 64];
    }

    // ---- stage ----
    {
        const float4* Gg = reinterpret_cast<const float4*>(G + tok0 * 32);
        for (int i = tid; i < 512; i += 256) {
            int t = i >> 3, p = i & 7;
            *reinterpret_cast<float4*>(&Gt[t][p * 4]) = Gg[i];
        }
        if (tid < 64) cumL[tid] = cumG[tok0 + tid];
        if (tid < 16) A2l[tid] = A[tid] * LOG2E;
    }
    const float Sc = S[b * CH + c];
    __syncthreads();

    // ---- phase 1: argT + Fq ----
    for (int i = tid; i < 1024; i += 256) {
        int t = i >> 4, n = i & 15;
        argT[t][n] = A2l[n] * cumL[t];
    }
    for (int i = tid; i < 1024; i += 256) {
        int nn = i >> 6, s = i & 63;
        Fq[nn][s] = Gt[s][nn] * exp2f(A2l[nn] * (Sc - cumL[s]));
    }
    __syncthreads();

    // ---- phase 2: build Mt (thread: fixed s = lane, t = 4k + w) ----
    {
        const int s = lane;
        float dBs[16], args[16];
#pragma unroll
        for (int n = 0; n < 16; ++n) { dBs[n] = Gt[s][n]; args[n] = argT[s][n]; }
        for (int k = 0; k < 16; ++k) {
            int t = 4 * k + w;
            const float4* Ct = reinterpret_cast<const float4*>(&Gt[t][16]);
            const float4* at = reinterpret_cast<const float4*>(&argT[t][0]);
            float acc = 0.f;
#pragma unroll
            for (int p = 0; p < 4; ++p) {
                float4 c4 = Ct[p], a4 = at[p];
                acc = fmaf(c4.x * dBs[4*p],   exp2f(a4.x - args[4*p]),   acc);
                acc = fmaf(c4.y * dBs[4*p+1], exp2f(a4.y - args[4*p+1]), acc);
                acc = fmaf(c4.z * dBs[4*p+2], exp2f(a4.z - args[4*p+2]), acc);
                acc = fmaf(c4.w * dBs[4*p+3], exp2f(a4.w - args[4*p+3]), acc);
            }
            Mt[t][s] = (s <= t) ? acc : 0.f;   // mask kills garbage for s>t
        }
    }
    __syncthreads();

    // ---- phase 3a: y_local = Mt @ X; wave w owns rows t=4k+w ----
    {
        float* yp = y + tok0 * Fdim + 2 * lane;
        // k<8: t <= 31 -> s<=31 -> 8 f4 (constant trip, X compile-time indexed)
        for (int k = 0; k < 8; ++k) {
            int t = 4 * k + w;
            const float4* Mrow = reinterpret_cast<const float4*>(&Mt[t][0]);
            float a0 = 0.f, a1 = 0.f, b0 = 0.f, b1 = 0.f;
#pragma unroll
            for (int s4 = 0; s4 < 8; ++s4) {
                float4 m4 = Mrow[s4];
                a0 = fmaf(m4.x, Xv[4*s4].x,     a0); b0 = fmaf(m4.x, Xv[4*s4].y,     b0);
                a1 = fmaf(m4.y, Xv[4*s4 + 1].x, a1); b1 = fmaf(m4.y, Xv[4*s4 + 1].y, b1);
                a0 = fmaf(m4.z, Xv[4*s4 + 2].x, a0); b0 = fmaf(m4.z, Xv[4*s4 + 2].y, b0);
                a1 = fmaf(m4.w, Xv[4*s4 + 3].x, a1); b1 = fmaf(m4.w, Xv[4*s4 + 3].y, b1);
            }
            yp[t * Fdim]     = a0 + a1;
            yp[t * Fdim + 1] = b0 + b1;
        }
        // k>=8: full 16 f4 (constant trip)
        for (int k = 8; k < 16; ++k) {
            int t = 4 * k + w;
            const float4* Mrow = reinterpret_cast<const float4*>(&Mt[t][0]);
            float a0 = 0.f, a1 = 0.f, b0 = 0.f, b1 = 0.f;
#pragma unroll
            for (int s4 = 0; s4 < 16; ++s4) {
                float4 m4 = Mrow[s4];
                a0 = fmaf(m4.x, Xv[4*s4].x,     a0); b0 = fmaf(m4.x, Xv[4*s4].y,     b0);
                a1 = fmaf(m4.y, Xv[4*s4 + 1].x, a1); b1 = fmaf(m4.y, Xv[4*s4 + 1].y, b1);
                a0 = fmaf(m4.z, Xv[4*s4 + 2].x, a0); b0 = fmaf(m4.z, Xv[4*s4 + 2].y, b0);
                a1 = fmaf(m4.w, Xv[4*s4 + 3].x, a1); b1 = fmaf(m4.w, Xv[4*s4 + 3].y, b1);
            }
            yp[t * Fdim]     = a0 + a1;
            yp[t * Fdim + 1] = b0 + b1;
        }
    }

    // ---- phase 3b: q = Fq @ X; wave w owns n = 4w..4w+3 ----
    {
        float qv0[4], qv1[4];
#pragma unroll
        for (int j = 0; j < 4; ++j) {
            const float4* Fr = reinterpret_cast<const float4*>(&Fq[4 * w + j][0]);
            float a0 = 0.f, a1 = 0.f, b0 = 0.f, b1 = 0.f;
#pragma unroll
            for (int s4 = 0; s4 < 16; ++s4) {
                float4 f4 = Fr[s4];
                a0 = fmaf(f4.x, Xv[4*s4].x,     a0); b0 = fmaf(f4.x, Xv[4*s4].y,     b0);
                a1 = fmaf(f4.y, Xv[4*s4 + 1].x, a1); b1 = fmaf(f4.y, Xv[4*s4 + 1].y, b1);
                a0 = fmaf(f4.z, Xv[4*s4 + 2].x, a0); b0 = fmaf(f4.z, Xv[4*s4 + 2].y, b0);
                a1 = fmaf(f4.w, Xv[4*s4 + 3].x, a1); b1 = fmaf(f4.w, Xv[4*s4 + 3].y, b1);
            }
            qv0[j] = a0 + a1;
            qv1[j] = b0 + b1;
        }
        float* qp0 = q + ((size_t)(b * CH + c) * Fdim + 2 * lane)     * 16 + 4 * w;
        float* qp1 = q + ((size_t)(b * CH + c) * Fdim + 2 * lane + 1) * 16 + 4 * w;
        *reinterpret_cast<float4*>(qp0) = make_float4(qv0[0], qv0[1], qv0[2], qv0[3]);
        *reinterpret_cast<float4*>(qp1) = make_float4(qv1[0], qv1[1], qv1[2], qv1[3]);
    }
}

__global__ __launch_bounds__(256) void k_chunkscan(
    const float* __restrict__ q, const float* __restrict__ S,
    const float* __restrict__ A, float* __restrict__ Hin)
{
    int id = blockIdx.x * 256 + threadIdx.x;   // 16384 = 8*128*16
    int b  = id >> 11;
    int fn = id & 2047;
    int n  = id & 15;
    float An = A[n];
    float H = 0.f;
    size_t qb = (size_t)b * CH * 2048 + fn;
    const float* Sb = S + b * CH;
    for (int cg = 0; cg < CH; cg += 16) {
        float Sr[16], qr[16];
#pragma unroll
        for (int i = 0; i < 16; ++i) {
            Sr[i] = Sb[cg + i];
            qr[i] = q[qb + (size_t)(cg + i) * 2048];
        }
#pragma unroll
        for (int i = 0; i < 16; ++i) {
            Hin[qb + (size_t)(cg + i) * 2048] = H;
            H = fmaf(__expf(An * Sr[i]), H, qr[i]);
        }
    }
}

// grid (CH, BTc) x 128 thr: y += E @ Hin, E rebuilt from C,cum
__global__ __launch_bounds__(128) void k_correct(
    const float* __restrict__ G, const float* __restrict__ cumG,
    const float* __restrict__ A, const float* __restrict__ Hin,
    float* __restrict__ y)
{
    __shared__ float El[LC][16];
    __shared__ float cumL[LC];
    const int c = blockIdx.x, b = blockIdx.y;
    const int f = threadIdx.x;
    const size_t tok0 = (size_t)b * Lseq + (size_t)c * LC;

    if (f < 64) cumL[f] = cumG[tok0 + f];

    float hv[16];
    const float4* hp = reinterpret_cast<const float4*>(Hin + ((size_t)(b * CH + c) * Fdim + f) * 16);
#pragma unroll
    for (int p = 0; p < 4; ++p) {
        float4 t4 = hp[p];
        hv[4*p] = t4.x; hv[4*p+1] = t4.y; hv[4*p+2] = t4.z; hv[4*p+3] = t4.w;
    }
    __syncthreads();

    for (int i = f; i < 1024; i += 128) {
        int t = i >> 4, n = i & 15;
        float A2n = A[n] * LOG2E;
        El[t][n] = G[(tok0 + t) * 32 + 16 + n] * exp2f(A2n * cumL[t]);
    }
    __syncthreads();

    float* yp = y + tok0 * Fdim + f;
#pragma unroll 4
    for (int t = 0; t < LC; ++t) {
        const float4* ep = reinterpret_cast<const float4*>(&El[t][0]);
        float acc = 0.f;
#pragma unroll
        for (int p = 0; p < 4; ++p) {
            float4 e4 = ep[p];
            acc = fmaf(e4.x, hv[4*p],     acc);
            acc = fmaf(e4.y, hv[4*p + 1], acc);
            acc = fmaf(e4.z, hv[4*p + 2], acc);
            acc = fmaf(e4.w, hv[4*p + 3], acc);
        }
        yp[t * Fdim] += acc;
    }
}

extern "C" void kernel_launch(void* const* d_in, const int* in_sizes, int n_in,
                              void* d_out, int out_size, void* d_ws, size_t ws_size,
                              hipStream_t stream) {
    const float* x  = (const float*)d_in[0];
    const float* Wb = (const float*)d_in[1];
    const float* bb = (const float*)d_in[2];
    const float* Wc = (const float*)d_in[3];
    const float* bc = (const float*)d_in[4];
    const float* Wd = (const float*)d_in[5];
    const float* bd = (const float*)d_in[6];
    const float* A  = (const float*)d_in[7];
    float* y = (float*)d_out;

    float* G    = (float*)d_ws;                            // 65536*32 = 8.4 MB
    float* q    = G    + (size_t)BTc * Lseq * 32;          // 8.4 MB
    float* Hin  = q    + (size_t)BTc * CH * Fdim * Ndim;   // 8.4 MB
    float* cumG = Hin  + (size_t)BTc * CH * Fdim * Ndim;   // 0.26 MB
    float* S    = cumG + (size_t)BTc * Lseq;               // 4 KB

    k_pre<<<dim3(512), 256, 0, stream>>>(x, Wb, bb, Wc, bc, Wd, bd, A, G, cumG, S);
    k_ymm<<<dim3(CH, BTc), 256, 0, stream>>>(x, G, cumG, S, A, y, q);
    k_chunkscan<<<dim3(BTc * Fdim * Ndim / 256), 256, 0, stream>>>(q, S, A, Hin);
    k_correct<<<dim3(CH, BTc), 128, 0, stream>>>(G, cumG, A, Hin, y);
}